// Round 4
// baseline (169.803 us; speedup 1.0000x reference)
//
#include <hip/hip_runtime.h>
#include <hip/hip_bf16.h>
#include <string.h>

// Problem constants
#define NB    4096      // batch rows
#define IND_  512       // feature dim
#define OUTD_ 512       // output dim (GEMM M, "o")
#define XCOLS 514       // P + IND
#define ND    25        // D^P
#define KTOT  12800     // IND_*ND
#define KT2B  12928     // KTOT + 128-col bias tail (fp8 bytes per Wf8 row)
#define NSPL  4         // split over 4 i-windows

// GEMM tiling (v6: 256x128 block, 8 waves x (32 rows x 128 cols),
//              ALL-REGISTER: no LDS, no barriers)
#define BM 256
#define BN 128

// prep_w tiling (R18-proven v2)
#define PWI 64
#define PWO 4
#define PWC (PWO * ND)   // 100 columns (o_l*25 + d)
#define T8P 112          // tile8 padded byte stride

typedef float  f32x4  __attribute__((ext_vector_type(4)));
typedef int    i32x4  __attribute__((ext_vector_type(4)));
typedef int    i32x8  __attribute__((ext_vector_type(8)));
typedef unsigned short u16x4 __attribute__((ext_vector_type(4)));
typedef unsigned int   u32x2 __attribute__((ext_vector_type(2)));

__device__ __forceinline__ unsigned short f2bf(float f) {
  unsigned int x = __float_as_uint(f);
  return (unsigned short)((x + 0x7fffu + ((x >> 16) & 1u)) >> 16);
}

__device__ __forceinline__ float bf2f(unsigned short u) {
  return __uint_as_float(((unsigned int)u) << 16);
}

__device__ __forceinline__ unsigned int pk_bf16(float a, float b) {
  return (unsigned int)f2bf(a) | ((unsigned int)f2bf(b) << 16);
}

// Software fp32 -> OCP e4m3fn, RNE, for v >= 0 (all values < 1.2).
__device__ __forceinline__ unsigned char f2fp8(float v) {
  if (v < 0.015625f) {
    return (unsigned char)__float2int_rn(v * 512.0f);
  }
  unsigned int u = __float_as_uint(v);
  u += 0x7ffffu + ((u >> 20) & 1u);
  int e = (int)(u >> 23) - 127 + 7;
  unsigned int m = (u >> 20) & 7u;
  return (unsigned char)((e << 3) | m);
}

__device__ __forceinline__ float basis_f(float t, int j) {
  switch (j) {
    case 0: return 1.0f;
    case 1: return t;
    case 2: return t * t;
    case 3: { float r = t - 0.33f; r = r > 0.0f ? r : 0.0f; return r * r; }
    default:{ float r = t - 0.66f; r = r > 0.0f ? r : 0.0f; return r * r; }
  }
}

// ---------------------------------------------------------------------------
// prep_all v3: same as R18-proven v2, except kb (fp32 [b][d]) is replaced by
// kbDT (fp32 [d][b]) holding the TELESCOPING difference kb[b,d]-kb[b,d+1]
// (kbDT[24][b] = kb[b][24]) — the gemm's flush consumes dk directly, and the
// d-major layout makes each iter's dk reads 4 hot cache lines per wave.
// ---------------------------------------------------------------------------
__global__ __launch_bounds__(256) void prep_all_kernel(
    const float* __restrict__ x, const float* __restrict__ W,
    const float* __restrict__ bias, unsigned char* __restrict__ Xf8,
    float* __restrict__ kbDT, unsigned char* __restrict__ kbT8,
    unsigned char* __restrict__ Wf8, float* __restrict__ out)
{
  __shared__ unsigned char tile8[PWI * T8P];   // 7 KB
  const int bid = blockIdx.x;
  const int tid = threadIdx.x;

  if (bid < 512) {
    const int lane = tid & 63;
    #pragma unroll
    for (int rr = 0; rr < 2; ++rr) {
      const int b = bid * 8 + (tid >> 6) * 2 + rr;
      const float* xr = x + (size_t)b * XCOLS;
      const float* fp = xr + 2 + lane * 8;
      float2 a0 = *(const float2*)(fp + 0);
      float2 a1 = *(const float2*)(fp + 2);
      float2 a2 = *(const float2*)(fp + 4);
      float2 a3 = *(const float2*)(fp + 6);
      float xf[8] = {a0.x, a0.y, a1.x, a1.y, a2.x, a2.y, a3.x, a3.y};
      u32x2 pk;
      pk[0] = (unsigned int)f2fp8(xf[0]) | ((unsigned int)f2fp8(xf[1]) << 8) |
              ((unsigned int)f2fp8(xf[2]) << 16) | ((unsigned int)f2fp8(xf[3]) << 24);
      pk[1] = (unsigned int)f2fp8(xf[4]) | ((unsigned int)f2fp8(xf[5]) << 8) |
              ((unsigned int)f2fp8(xf[6]) << 16) | ((unsigned int)f2fp8(xf[7]) << 24);
      *reinterpret_cast<u32x2*>(Xf8 + (size_t)b * IND_ + lane * 8) = pk;

      float t0 = xr[0], t1 = xr[1];
      if (lane < 2) out[(size_t)b * XCOLS + lane] = (lane == 0) ? t0 : t1;
      {
        // telescoping difference dk_d = kv_d - kv_{d+1} (kv_25 := 0)
        int d1 = lane / 5, d2 = lane - d1 * 5;
        float kvd = basis_f(t0, d1) * basis_f(t1, d2);
        float kvn = 0.0f;
        if (lane < 24) {
          int e1 = (lane + 1) / 5, e2 = (lane + 1) - e1 * 5;
          kvn = basis_f(t0, e1) * basis_f(t1, e2);
        }
        if (lane < ND) kbDT[(size_t)lane * NB + b] = kvd - kvn;
      }
      {
        int ta = 2 * lane, tb = 2 * lane + 1;
        unsigned char ba = 0, bb = 0;
        if (ta < ND) { int d1 = ta / 5, d2 = ta - d1 * 5;
                       ba = f2fp8(basis_f(t0, d1) * basis_f(t1, d2)); }
        if (tb < ND) { int d1 = tb / 5, d2 = tb - d1 * 5;
                       bb = f2fp8(basis_f(t0, d1) * basis_f(t1, d2)); }
        *(unsigned short*)(kbT8 + (size_t)b * 128 + 2 * lane) =
            (unsigned short)ba | ((unsigned short)bb << 8);
      }
    }
  } else {
    const int pw = bid - 512;
    const int i0 = (pw & 7) * PWI;
    const int o0 = (pw >> 3) * PWO;

    for (int t = tid; t < PWI * (PWC / 4); t += 256) {
      int il = t / (PWC / 4);
      int c4 = t - il * (PWC / 4);
      float4 v = *(const float4*)(W + ((size_t)(i0 + il) * OUTD_ + o0) * ND + c4 * 4);
      unsigned int pk = (unsigned int)f2fp8(v.x) | ((unsigned int)f2fp8(v.y) << 8) |
                        ((unsigned int)f2fp8(v.z) << 16) | ((unsigned int)f2fp8(v.w) << 24);
      *(unsigned int*)&tile8[il * T8P + c4 * 4] = pk;
    }
    __syncthreads();

    for (int g = tid; g < PWC * (PWI / 8); g += 256) {
      int c  = g >> 3;
      int ig = g & 7;
      int d  = c % 25;
      int o_l = c / 25;
      unsigned long long v = 0;
      #pragma unroll
      for (int jj = 0; jj < 8; ++jj)
        v |= (unsigned long long)tile8[(ig * 8 + jj) * T8P + c] << (8 * jj);
      size_t rowb = (size_t)(o0 + o_l) * KT2B + (size_t)d * IND_ + i0;
      *reinterpret_cast<unsigned long long*>(Wf8 + rowb + ig * 8) = v;
    }

    if ((pw & 7) == 0) {
      int o = o0 + (tid >> 6);
      int p = tid & 63;
      int ta = 2 * p, tb = 2 * p + 1;
      unsigned char ba = (ta < ND) ? f2fp8(bias[o * ND + ta]) : (unsigned char)0;
      unsigned char bb = (tb < ND) ? f2fp8(bias[o * ND + tb]) : (unsigned char)0;
      *(unsigned short*)(Wf8 + (size_t)o * KT2B + KTOT + 2 * p) =
          (unsigned short)ba | ((unsigned short)bb << 8);
    }
  }
}

// ---------------------------------------------------------------------------
// gemm_mx v6: ALL-REGISTER, barrier-free, LDS-free.
//
// R21 post-mortem: per-iter time was pinned at ~3900-4400 cyc across R0-R3
// no matter what (staging volume, occupancy, depth, vmcnt, LDS read volume).
// Common denominator: the barrier-locked LDS-mediated iteration — 8 waves
// re-align every K-step, so LDS / MFMA / flush phases never cross-overlap.
//
// v6 makes each wave fully self-contained: wave w owns A-rows
// [o0+32w, o0+32w+32) x all 128 b-cols.  A fragments are loaded straight
// from L2 into registers (4x global_load_dwordx4 per iter per thread,
// double-buffered one full iteration ahead ≈1100 cyc > L2 latency); each
// A-row's 128-B K-window is exactly one cache line, fully consumed.
// B (Xf8) is loaded once into bfr[8] (v5-proven).  kv flush uses the
// precomputed telescoping dk from kbDT[d][b] (8 scalar loads/iter, 4 hot
// L2 lines per wave).  Bias tail (iw==3) direct-loads its fragments after
// the main loop (bfr dead there -> registers reuse).
// NO LDS. NO barriers. NO DMA. NO asm waitcnt (compiler tracks all deps).
// Waves free-run: the MFMA pipe (1104 cyc/SIMD-iter) is the only shared
// serial resource; flush VALU and VMEM run underneath.
// Regs ~240 (bfr 64 + acc 64 + fin 64 + A-dbuf 32 + dk 8 + ptrs) ≤ 256
// (2 waves/SIMD via __launch_bounds__(512,2)).
// Grid 256 = (bx,iw) on id&7 (same-XCD blocks share one A-panel in L2)
// x 32 b-tiles.
// ---------------------------------------------------------------------------
__global__ __launch_bounds__(512, 2) void gemm_mx_kernel(
    const unsigned char* __restrict__ Wf8, const unsigned char* __restrict__ Xf8,
    const float* __restrict__ kbDT, const unsigned char* __restrict__ kbT8,
    unsigned short* __restrict__ Pb)
{
  const int tid  = threadIdx.x;
  const int lane = tid & 63;
  const int w    = tid >> 6;            // [0,8)
  const int l15  = lane & 15;
  const int quad = lane >> 4;

  const int id  = blockIdx.x;           // [0,256)
  const int bx  = id & 1;               // o-tile [0,2)
  const int iw  = (id >> 1) & 3;        // i-window (split) [0,4)
  const int by  = id >> 3;              // b-tile [0,32)

  const int o0 = bx * BM;
  const int b0 = by * BN;
  const bool tail = (iw == 3);

  const int wr = w * 32;                // wave's 32 A-rows

  // helper: load a 32-B A/B fragment (one row's K-quad window) into i32x8
  auto load8 = [](const unsigned char* p) -> i32x8 {
    i32x4 lo = *reinterpret_cast<const i32x4*>(p);
    i32x4 hi = *reinterpret_cast<const i32x4*>(p + 16);
    i32x8 v;
    v[0] = lo[0]; v[1] = lo[1]; v[2] = lo[2]; v[3] = lo[3];
    v[4] = hi[0]; v[5] = hi[1]; v[6] = hi[2]; v[7] = hi[3];
    return v;
  };

  // ---- B fragments once (held for the whole kernel) ----
  i32x8 bfr[8];
  #pragma unroll
  for (int nf = 0; nf < 8; ++nf)
    bfr[nf] = load8(Xf8 + (size_t)(b0 + nf * 16 + l15) * IND_ + iw * 128 + quad * 32);

  // ---- A row pointers (mf = 0,1); advance +1024 per unrolled-2 pass ----
  const unsigned char* aP0 =
      Wf8 + (size_t)(o0 + wr + l15) * KT2B + iw * 128 + quad * 32;
  const unsigned char* aP1 = aP0 + (size_t)16 * KT2B;

  // ---- dk pointer: kbDT[d][b0 + nf*16 + l15]; advance +NB per iter ----
  const float* dkP = kbDT + b0 + l15;

  f32x4 acc[2][8], fin[2][8];
  #pragma unroll
  for (int mf = 0; mf < 2; ++mf)
    #pragma unroll
    for (int nf = 0; nf < 8; ++nf) { acc[mf][nf] = (f32x4)0.0f; fin[mf][nf] = (f32x4)0.0f; }

  // 16 MFMAs (telescoping: acc never reset) + dk-scaled flush into fin
  auto mfma_flush = [&](const i32x8 (&a)[2], const float (&dk)[8]) {
    #pragma unroll
    for (int mf = 0; mf < 2; ++mf)
      #pragma unroll
      for (int nf = 0; nf < 8; ++nf)
        acc[mf][nf] = __builtin_amdgcn_mfma_scale_f32_16x16x128_f8f6f4(
            a[mf], bfr[nf], acc[mf][nf],
            0, 0, 0, 0x7f7f7f7f, 0, 0x7f7f7f7f);
    #pragma unroll
    for (int mf = 0; mf < 2; ++mf)
      #pragma unroll
      for (int nf = 0; nf < 8; ++nf)
        #pragma unroll
        for (int r = 0; r < 4; ++r)
          fin[mf][nf][r] += dk[nf] * acc[mf][nf][r];
  };

  // ---- prologue: A(0) into buffer a0 ----
  i32x8 a0[2], a1[2];
  a0[0] = load8(aP0);
  a0[1] = load8(aP1);

  // ---- main loop: 24 iters in 12 unrolled-2 passes, static double-buffer.
  // Pass invariant: aP* point at A(n) col-base; dkP at dk(n) row.
  for (int pass = 0; pass < 12; ++pass) {
    // iter n (even): compute on a0, prefetch A(n+1) -> a1
    a1[0] = load8(aP0 + 512);
    a1[1] = load8(aP1 + 512);
    float dka[8];
    #pragma unroll
    for (int nf = 0; nf < 8; ++nf) dka[nf] = dkP[nf * 16];
    mfma_flush(a0, dka);

    // iter n+1 (odd): compute on a1, prefetch A(n+2) -> a0
    a0[0] = load8(aP0 + 1024);
    a0[1] = load8(aP1 + 1024);
    float dkb[8];
    #pragma unroll
    for (int nf = 0; nf < 8; ++nf) dkb[nf] = dkP[NB + nf * 16];
    mfma_flush(a1, dkb);

    aP0 += 1024; aP1 += 1024;
    dkP += 2 * NB;
  }

  // ---- peeled iter 24 (a0 holds A(24)); tail prefetch for iw==3 ----
  // aP* now point at A(24) col-base = iw*128 + 12288 (+row,quad).  For
  // iw==3 the bias block lives at col KTOT=12800 -> offset +128.
  if (tail) {
    a1[0] = load8(aP0 + 128);
    a1[1] = load8(aP1 + 128);
  }
  {
    float dkl[8];
    #pragma unroll
    for (int nf = 0; nf < 8; ++nf) dkl[nf] = dkP[nf * 16];
    mfma_flush(a0, dkl);
  }

  // ---- bias K-tail (iw==3): B = kbT8 fragments, accumulate into fin ----
  if (tail) {
    i32x8 bft[8];
    #pragma unroll
    for (int nf = 0; nf < 8; ++nf)
      bft[nf] = load8(kbT8 + (size_t)(b0 + nf * 16 + l15) * 128 + quad * 32);
    #pragma unroll
    for (int mf = 0; mf < 2; ++mf)
      #pragma unroll
      for (int nf = 0; nf < 8; ++nf)
        fin[mf][nf] = __builtin_amdgcn_mfma_scale_f32_16x16x128_f8f6f4(
            a1[mf], bft[nf], fin[mf][nf],
            0, 0, 0, 0x7f7f7f7f, 0, 0x7f7f7f7f);
  }

  // ---- store partial as bf16 ----
  unsigned short* Pz = Pb + (size_t)iw * NB * OUTD_;
  #pragma unroll
  for (int mf = 0; mf < 2; ++mf)
    #pragma unroll
    for (int nf = 0; nf < 8; ++nf) {
      int bg = b0 + nf * 16 + l15;
      int og = o0 + wr + mf * 16 + quad * 4;
      u32x2 pk;
      pk[0] = pk_bf16(fin[mf][nf][0], fin[mf][nf][1]);
      pk[1] = pk_bf16(fin[mf][nf][2], fin[mf][nf][3]);
      *reinterpret_cast<u32x2*>(&Pz[(size_t)bg * OUTD_ + og]) = pk;
    }
}

// ---------------------------------------------------------------------------
// epilogue: out[b][2+o..2+o+3] = relu(P0+P1+P2+P3)  (bias in K-tail)
// ---------------------------------------------------------------------------
__global__ __launch_bounds__(256) void epilogue_kernel(
    const unsigned short* __restrict__ Pb, float* __restrict__ out)
{
  const int idx = (blockIdx.x * 256 + threadIdx.x) * 4;   // < 4096*512
  const int b = idx >> 9;
  const int o = idx & 511;
  const size_t ps = (size_t)NB * OUTD_;
  float s[4] = {0.0f, 0.0f, 0.0f, 0.0f};
  #pragma unroll
  for (int z = 0; z < NSPL; ++z) {
    u16x4 v = *reinterpret_cast<const u16x4*>(&Pb[z * ps + idx]);
    #pragma unroll
    for (int e = 0; e < 4; ++e) s[e] += bf2f(v[e]);
  }
  float* op = out + (size_t)b * XCOLS + 2 + o;   // 8B-aligned
  float2 lo, hi;
  lo.x = s[0] > 0.0f ? s[0] : 0.0f;
  lo.y = s[1] > 0.0f ? s[1] : 0.0f;
  hi.x = s[2] > 0.0f ? s[2] : 0.0f;
  hi.y = s[3] > 0.0f ? s[3] : 0.0f;
  *(float2*)op = lo;
  *(float2*)(op + 2) = hi;
}

// ---------------------------------------------------------------------------
extern "C" void kernel_launch(void* const* d_in, const int* in_sizes, int n_in,
                              void* d_out, int out_size, void* d_ws, size_t ws_size,
                              hipStream_t stream) {
  const float* x    = (const float*)d_in[0];   // 4096 x 514
  const float* W    = (const float*)d_in[1];   // 512 x 512 x 25
  const float* bias = (const float*)d_in[2];   // 512 x 25
  float* out = (float*)d_out;
  char* ws = (char*)d_ws;

  // ws layout (bytes):
  //   Xf8 2,097,152 | Wf8 512*12928 = 6,619,136 | kbDT 25*4096*4 = 409,600
  //   kbT8 524,288 | Pb 4*4096*512*2 = 16,777,216   (total ~26.4 MB)
  const size_t xf_off  = 0;
  const size_t wf_off  = 2097152;
  const size_t kb_off  = wf_off + (size_t)OUTD_ * KT2B;
  const size_t kbt_off = kb_off + 409600;
  const size_t p_off   = kbt_off + (size_t)NB * 128;
  unsigned char* Xf8  = (unsigned char*)(ws + xf_off);
  unsigned char* Wf8  = (unsigned char*)(ws + wf_off);
  float* kbDT         = (float*)(ws + kb_off);
  unsigned char* kbT8 = (unsigned char*)(ws + kbt_off);
  unsigned short* Pb  = (unsigned short*)(ws + p_off);

  prep_all_kernel<<<1536, 256, 0, stream>>>(x, W, bias, Xf8, kbDT, kbT8, Wf8, out);
  gemm_mx_kernel<<<256, 512, 0, stream>>>(Wf8, Xf8, kbDT, kbT8, Pb);
  epilogue_kernel<<<(NB * OUTD_) / 1024, 256, 0, stream>>>(Pb, out);
}

// Round 5
// 167.622 us; speedup vs baseline: 1.0130x; 1.0130x over previous
//
#include <hip/hip_runtime.h>
#include <hip/hip_bf16.h>
#include <string.h>

// Problem constants
#define NB    4096      // batch rows
#define IND_  512       // feature dim
#define OUTD_ 512       // output dim (GEMM M, "o")
#define XCOLS 514       // P + IND
#define ND    25        // D^P
#define KTOT  12800     // IND_*ND
#define KT2B  12928     // KTOT + 128-col bias tail (fp8 bytes per Wf8 row)
#define NSPL  4         // split over 4 i-windows

// GEMM tiling (v7: 128x128 block, 4 waves x (32 rows x 128 cols),
//              ALL-REGISTER: no LDS, no barriers; 2 blocks/CU)
#define BM 128
#define BN 128

// prep_w tiling (R18-proven v2)
#define PWI 64
#define PWO 4
#define PWC (PWO * ND)   // 100 columns (o_l*25 + d)
#define T8P 112          // tile8 padded byte stride

typedef float  f32x4  __attribute__((ext_vector_type(4)));
typedef int    i32x4  __attribute__((ext_vector_type(4)));
typedef int    i32x8  __attribute__((ext_vector_type(8)));
typedef unsigned short u16x4 __attribute__((ext_vector_type(4)));
typedef unsigned int   u32x2 __attribute__((ext_vector_type(2)));

__device__ __forceinline__ unsigned short f2bf(float f) {
  unsigned int x = __float_as_uint(f);
  return (unsigned short)((x + 0x7fffu + ((x >> 16) & 1u)) >> 16);
}

__device__ __forceinline__ float bf2f(unsigned short u) {
  return __uint_as_float(((unsigned int)u) << 16);
}

__device__ __forceinline__ unsigned int pk_bf16(float a, float b) {
  return (unsigned int)f2bf(a) | ((unsigned int)f2bf(b) << 16);
}

// Software fp32 -> OCP e4m3fn, RNE, for v >= 0 (all values < 1.2).
__device__ __forceinline__ unsigned char f2fp8(float v) {
  if (v < 0.015625f) {
    return (unsigned char)__float2int_rn(v * 512.0f);
  }
  unsigned int u = __float_as_uint(v);
  u += 0x7ffffu + ((u >> 20) & 1u);
  int e = (int)(u >> 23) - 127 + 7;
  unsigned int m = (u >> 20) & 7u;
  return (unsigned char)((e << 3) | m);
}

__device__ __forceinline__ float basis_f(float t, int j) {
  switch (j) {
    case 0: return 1.0f;
    case 1: return t;
    case 2: return t * t;
    case 3: { float r = t - 0.33f; r = r > 0.0f ? r : 0.0f; return r * r; }
    default:{ float r = t - 0.66f; r = r > 0.0f ? r : 0.0f; return r * r; }
  }
}

// ---------------------------------------------------------------------------
// prep_all v3 (unchanged from R4 — proven): kbDT (fp32 [d][b]) holds the
// TELESCOPING difference kb[b,d]-kb[b,d+1] (kbDT[24][b] = kb[b][24]).
// ---------------------------------------------------------------------------
__global__ __launch_bounds__(256) void prep_all_kernel(
    const float* __restrict__ x, const float* __restrict__ W,
    const float* __restrict__ bias, unsigned char* __restrict__ Xf8,
    float* __restrict__ kbDT, unsigned char* __restrict__ kbT8,
    unsigned char* __restrict__ Wf8, float* __restrict__ out)
{
  __shared__ unsigned char tile8[PWI * T8P];   // 7 KB
  const int bid = blockIdx.x;
  const int tid = threadIdx.x;

  if (bid < 512) {
    const int lane = tid & 63;
    #pragma unroll
    for (int rr = 0; rr < 2; ++rr) {
      const int b = bid * 8 + (tid >> 6) * 2 + rr;
      const float* xr = x + (size_t)b * XCOLS;
      const float* fp = xr + 2 + lane * 8;
      float2 a0 = *(const float2*)(fp + 0);
      float2 a1 = *(const float2*)(fp + 2);
      float2 a2 = *(const float2*)(fp + 4);
      float2 a3 = *(const float2*)(fp + 6);
      float xf[8] = {a0.x, a0.y, a1.x, a1.y, a2.x, a2.y, a3.x, a3.y};
      u32x2 pk;
      pk[0] = (unsigned int)f2fp8(xf[0]) | ((unsigned int)f2fp8(xf[1]) << 8) |
              ((unsigned int)f2fp8(xf[2]) << 16) | ((unsigned int)f2fp8(xf[3]) << 24);
      pk[1] = (unsigned int)f2fp8(xf[4]) | ((unsigned int)f2fp8(xf[5]) << 8) |
              ((unsigned int)f2fp8(xf[6]) << 16) | ((unsigned int)f2fp8(xf[7]) << 24);
      *reinterpret_cast<u32x2*>(Xf8 + (size_t)b * IND_ + lane * 8) = pk;

      float t0 = xr[0], t1 = xr[1];
      if (lane < 2) out[(size_t)b * XCOLS + lane] = (lane == 0) ? t0 : t1;
      {
        // telescoping difference dk_d = kv_d - kv_{d+1} (kv_25 := 0)
        int d1 = lane / 5, d2 = lane - d1 * 5;
        float kvd = basis_f(t0, d1) * basis_f(t1, d2);
        float kvn = 0.0f;
        if (lane < 24) {
          int e1 = (lane + 1) / 5, e2 = (lane + 1) - e1 * 5;
          kvn = basis_f(t0, e1) * basis_f(t1, e2);
        }
        if (lane < ND) kbDT[(size_t)lane * NB + b] = kvd - kvn;
      }
      {
        int ta = 2 * lane, tb = 2 * lane + 1;
        unsigned char ba = 0, bb = 0;
        if (ta < ND) { int d1 = ta / 5, d2 = ta - d1 * 5;
                       ba = f2fp8(basis_f(t0, d1) * basis_f(t1, d2)); }
        if (tb < ND) { int d1 = tb / 5, d2 = tb - d1 * 5;
                       bb = f2fp8(basis_f(t0, d1) * basis_f(t1, d2)); }
        *(unsigned short*)(kbT8 + (size_t)b * 128 + 2 * lane) =
            (unsigned short)ba | ((unsigned short)bb << 8);
      }
    }
  } else {
    const int pw = bid - 512;
    const int i0 = (pw & 7) * PWI;
    const int o0 = (pw >> 3) * PWO;

    for (int t = tid; t < PWI * (PWC / 4); t += 256) {
      int il = t / (PWC / 4);
      int c4 = t - il * (PWC / 4);
      float4 v = *(const float4*)(W + ((size_t)(i0 + il) * OUTD_ + o0) * ND + c4 * 4);
      unsigned int pk = (unsigned int)f2fp8(v.x) | ((unsigned int)f2fp8(v.y) << 8) |
                        ((unsigned int)f2fp8(v.z) << 16) | ((unsigned int)f2fp8(v.w) << 24);
      *(unsigned int*)&tile8[il * T8P + c4 * 4] = pk;
    }
    __syncthreads();

    for (int g = tid; g < PWC * (PWI / 8); g += 256) {
      int c  = g >> 3;
      int ig = g & 7;
      int d  = c % 25;
      int o_l = c / 25;
      unsigned long long v = 0;
      #pragma unroll
      for (int jj = 0; jj < 8; ++jj)
        v |= (unsigned long long)tile8[(ig * 8 + jj) * T8P + c] << (8 * jj);
      size_t rowb = (size_t)(o0 + o_l) * KT2B + (size_t)d * IND_ + i0;
      *reinterpret_cast<unsigned long long*>(Wf8 + rowb + ig * 8) = v;
    }

    if ((pw & 7) == 0) {
      int o = o0 + (tid >> 6);
      int p = tid & 63;
      int ta = 2 * p, tb = 2 * p + 1;
      unsigned char ba = (ta < ND) ? f2fp8(bias[o * ND + ta]) : (unsigned char)0;
      unsigned char bb = (tb < ND) ? f2fp8(bias[o * ND + tb]) : (unsigned char)0;
      *(unsigned short*)(Wf8 + (size_t)o * KT2B + KTOT + 2 * p) =
          (unsigned short)ba | ((unsigned short)bb << 8);
    }
  }
}

// ---------------------------------------------------------------------------
// gemm_mx v7: ALL-REGISTER (v6 dataflow, numerically proven in R4) re-fit
// to the register file.
//
// R22 post-mortem of v6: VGPR_Count=128 + 78 MB scratch writes -> the
// 512-thread __launch_bounds__(512,2) resolved to a 4-waves/SIMD budget
// (128 VGPR cap) while the design needs ~240.  All the regression was
// register spill; correctness and dataflow were fine (identical absmax).
//
// v7: 256-thread blocks (4 waves), __launch_bounds__(256,2) — documented
// semantics: 2 blocks/CU, 2 waves/SIMD, 256-VGPR cap.  Demand ~240 fits.
// Block tile 128x128 (4 waves x 32o x 128b, per-wave layout unchanged).
// Grid 512 = 4(o) x 4(iw) x 32(b) = exactly 2 blocks/CU.
// XCD mapping: id&7 = XCD; each XCD serves 2 (o,iw) combos -> 2 A-panels
// (0.86 MB) + 2 X-slices (1 MB) L2-resident; A L2 traffic 218 MB ≈ 6.3 us
// < MFMA floor 11.5 us (2 waves/SIMD x 25 x 16 MFMA x 34.5 cyc).
// NO LDS / barriers / DMA / asm.  A double-buffered one iter (552 cyc)
// ahead >> L2 latency; dk loaded before the MFMA block covers its use.
// ---------------------------------------------------------------------------
__global__ __launch_bounds__(256, 2) void gemm_mx_kernel(
    const unsigned char* __restrict__ Wf8, const unsigned char* __restrict__ Xf8,
    const float* __restrict__ kbDT, const unsigned char* __restrict__ kbT8,
    unsigned short* __restrict__ Pb)
{
  const int tid  = threadIdx.x;
  const int lane = tid & 63;
  const int w    = tid >> 6;            // [0,4)
  const int l15  = lane & 15;
  const int quad = lane >> 4;

  const int id    = blockIdx.x;         // [0,512)
  const int xcd   = id & 7;
  const int g     = id >> 3;            // [0,64)
  const int combo = xcd + 8 * (g & 1);  // [0,16): (o-tile, iw)
  const int by    = g >> 1;             // [0,32)
  const int ox    = combo & 3;          // o-tile [0,4)
  const int iw    = combo >> 2;         // i-window (split) [0,4)

  const int o0 = ox * BM;
  const int b0 = by * BN;
  const bool tail = (iw == 3);

  const int wr = w * 32;                // wave's 32 A-rows within the block

  // helper: load a 32-B A/B fragment (one row's K-quad window) into i32x8
  auto load8 = [](const unsigned char* p) -> i32x8 {
    i32x4 lo = *reinterpret_cast<const i32x4*>(p);
    i32x4 hi = *reinterpret_cast<const i32x4*>(p + 16);
    i32x8 v;
    v[0] = lo[0]; v[1] = lo[1]; v[2] = lo[2]; v[3] = lo[3];
    v[4] = hi[0]; v[5] = hi[1]; v[6] = hi[2]; v[7] = hi[3];
    return v;
  };

  // ---- B fragments once (held for the whole kernel) ----
  i32x8 bfr[8];
  #pragma unroll
  for (int nf = 0; nf < 8; ++nf)
    bfr[nf] = load8(Xf8 + (size_t)(b0 + nf * 16 + l15) * IND_ + iw * 128 + quad * 32);

  // ---- A row pointers (mf = 0,1); advance +1024 per unrolled-2 pass ----
  const unsigned char* aP0 =
      Wf8 + (size_t)(o0 + wr + l15) * KT2B + iw * 128 + quad * 32;
  const unsigned char* aP1 = aP0 + (size_t)16 * KT2B;

  // ---- dk pointer: kbDT[d][b0 + nf*16 + l15]; advance +NB per iter ----
  const float* dkP = kbDT + b0 + l15;

  f32x4 acc[2][8], fin[2][8];
  #pragma unroll
  for (int mf = 0; mf < 2; ++mf)
    #pragma unroll
    for (int nf = 0; nf < 8; ++nf) { acc[mf][nf] = (f32x4)0.0f; fin[mf][nf] = (f32x4)0.0f; }

  // 16 MFMAs (telescoping: acc never reset) + dk-scaled flush into fin
  auto mfma_flush = [&](const i32x8 (&a)[2], const float (&dk)[8]) {
    #pragma unroll
    for (int mf = 0; mf < 2; ++mf)
      #pragma unroll
      for (int nf = 0; nf < 8; ++nf)
        acc[mf][nf] = __builtin_amdgcn_mfma_scale_f32_16x16x128_f8f6f4(
            a[mf], bfr[nf], acc[mf][nf],
            0, 0, 0, 0x7f7f7f7f, 0, 0x7f7f7f7f);
    #pragma unroll
    for (int mf = 0; mf < 2; ++mf)
      #pragma unroll
      for (int nf = 0; nf < 8; ++nf)
        #pragma unroll
        for (int r = 0; r < 4; ++r)
          fin[mf][nf][r] += dk[nf] * acc[mf][nf][r];
  };

  // ---- prologue: A(0) into buffer a0 ----
  i32x8 a0[2], a1[2];
  a0[0] = load8(aP0);
  a0[1] = load8(aP1);

  // ---- main loop: 24 iters in 12 unrolled-2 passes, static double-buffer.
  // Pass invariant: aP* point at A(n) col-base; dkP at dk(n) row.
  for (int pass = 0; pass < 12; ++pass) {
    // iter n (even): compute on a0, prefetch A(n+1) -> a1
    a1[0] = load8(aP0 + 512);
    a1[1] = load8(aP1 + 512);
    float dka[8];
    #pragma unroll
    for (int nf = 0; nf < 8; ++nf) dka[nf] = dkP[nf * 16];
    mfma_flush(a0, dka);

    // iter n+1 (odd): compute on a1, prefetch A(n+2) -> a0
    a0[0] = load8(aP0 + 1024);
    a0[1] = load8(aP1 + 1024);
    float dkb[8];
    #pragma unroll
    for (int nf = 0; nf < 8; ++nf) dkb[nf] = dkP[NB + nf * 16];
    mfma_flush(a1, dkb);

    aP0 += 1024; aP1 += 1024;
    dkP += 2 * NB;
  }

  // ---- peeled iter 24 (a0 holds A(24)); tail prefetch for iw==3 ----
  // aP* now point at A(24) col-base = iw*128 + 12288 (+row,quad).  For
  // iw==3 the bias block lives at col KTOT=12800 -> offset +128.
  if (tail) {
    a1[0] = load8(aP0 + 128);
    a1[1] = load8(aP1 + 128);
  }
  {
    float dkl[8];
    #pragma unroll
    for (int nf = 0; nf < 8; ++nf) dkl[nf] = dkP[nf * 16];
    mfma_flush(a0, dkl);
  }

  // ---- bias K-tail (iw==3): B = kbT8 fragments, accumulate into fin ----
  if (tail) {
    i32x8 bft[8];
    #pragma unroll
    for (int nf = 0; nf < 8; ++nf)
      bft[nf] = load8(kbT8 + (size_t)(b0 + nf * 16 + l15) * 128 + quad * 32);
    #pragma unroll
    for (int mf = 0; mf < 2; ++mf)
      #pragma unroll
      for (int nf = 0; nf < 8; ++nf)
        fin[mf][nf] = __builtin_amdgcn_mfma_scale_f32_16x16x128_f8f6f4(
            a1[mf], bft[nf], fin[mf][nf],
            0, 0, 0, 0x7f7f7f7f, 0, 0x7f7f7f7f);
  }

  // ---- store partial as bf16 ----
  unsigned short* Pz = Pb + (size_t)iw * NB * OUTD_;
  #pragma unroll
  for (int mf = 0; mf < 2; ++mf)
    #pragma unroll
    for (int nf = 0; nf < 8; ++nf) {
      int bg = b0 + nf * 16 + l15;
      int og = o0 + wr + mf * 16 + quad * 4;
      u32x2 pk;
      pk[0] = pk_bf16(fin[mf][nf][0], fin[mf][nf][1]);
      pk[1] = pk_bf16(fin[mf][nf][2], fin[mf][nf][3]);
      *reinterpret_cast<u32x2*>(&Pz[(size_t)bg * OUTD_ + og]) = pk;
    }
}

// ---------------------------------------------------------------------------
// epilogue: out[b][2+o..2+o+3] = relu(P0+P1+P2+P3)  (bias in K-tail)
// ---------------------------------------------------------------------------
__global__ __launch_bounds__(256) void epilogue_kernel(
    const unsigned short* __restrict__ Pb, float* __restrict__ out)
{
  const int idx = (blockIdx.x * 256 + threadIdx.x) * 4;   // < 4096*512
  const int b = idx >> 9;
  const int o = idx & 511;
  const size_t ps = (size_t)NB * OUTD_;
  float s[4] = {0.0f, 0.0f, 0.0f, 0.0f};
  #pragma unroll
  for (int z = 0; z < NSPL; ++z) {
    u16x4 v = *reinterpret_cast<const u16x4*>(&Pb[z * ps + idx]);
    #pragma unroll
    for (int e = 0; e < 4; ++e) s[e] += bf2f(v[e]);
  }
  float* op = out + (size_t)b * XCOLS + 2 + o;   // 8B-aligned
  float2 lo, hi;
  lo.x = s[0] > 0.0f ? s[0] : 0.0f;
  lo.y = s[1] > 0.0f ? s[1] : 0.0f;
  hi.x = s[2] > 0.0f ? s[2] : 0.0f;
  hi.y = s[3] > 0.0f ? s[3] : 0.0f;
  *(float2*)op = lo;
  *(float2*)(op + 2) = hi;
}

// ---------------------------------------------------------------------------
extern "C" void kernel_launch(void* const* d_in, const int* in_sizes, int n_in,
                              void* d_out, int out_size, void* d_ws, size_t ws_size,
                              hipStream_t stream) {
  const float* x    = (const float*)d_in[0];   // 4096 x 514
  const float* W    = (const float*)d_in[1];   // 512 x 512 x 25
  const float* bias = (const float*)d_in[2];   // 512 x 25
  float* out = (float*)d_out;
  char* ws = (char*)d_ws;

  // ws layout (bytes):
  //   Xf8 2,097,152 | Wf8 512*12928 = 6,619,136 | kbDT 25*4096*4 = 409,600
  //   kbT8 524,288 | Pb 4*4096*512*2 = 16,777,216   (total ~26.4 MB)
  const size_t xf_off  = 0;
  const size_t wf_off  = 2097152;
  const size_t kb_off  = wf_off + (size_t)OUTD_ * KT2B;
  const size_t kbt_off = kb_off + 409600;
  const size_t p_off   = kbt_off + (size_t)NB * 128;
  unsigned char* Xf8  = (unsigned char*)(ws + xf_off);
  unsigned char* Wf8  = (unsigned char*)(ws + wf_off);
  float* kbDT         = (float*)(ws + kb_off);
  unsigned char* kbT8 = (unsigned char*)(ws + kbt_off);
  unsigned short* Pb  = (unsigned short*)(ws + p_off);

  prep_all_kernel<<<1536, 256, 0, stream>>>(x, W, bias, Xf8, kbDT, kbT8, Wf8, out);
  gemm_mx_kernel<<<512, 256, 0, stream>>>(Wf8, Xf8, kbDT, kbT8, Pb);
  epilogue_kernel<<<(NB * OUTD_) / 1024, 256, 0, stream>>>(Pb, out);
}

// Round 6
// 149.532 us; speedup vs baseline: 1.1356x; 1.1210x over previous
//
#include <hip/hip_runtime.h>
#include <hip/hip_bf16.h>
#include <string.h>

// Problem constants
#define NB    4096      // batch rows
#define IND_  512       // feature dim
#define OUTD_ 512       // output dim (GEMM M, "o")
#define XCOLS 514       // P + IND
#define ND    25        // D^P
#define KTOT  12800     // IND_*ND
#define KT2B  12928     // KTOT + 128-col bias tail (fp8 bytes per Wf8 row)
#define NSPL  4         // split over 4 i-windows

// GEMM tiling (v8: 64x128 block, 4 waves x (32o x 64b),
//              ALL-REGISTER: no LDS, no barriers; ~160 regs/wave)
#define BM 64
#define BN 128

// prep_w tiling (R18-proven v2)
#define PWI 64
#define PWO 4
#define PWC (PWO * ND)   // 100 columns (o_l*25 + d)
#define T8P 112          // tile8 padded byte stride

typedef float  f32x4  __attribute__((ext_vector_type(4)));
typedef int    i32x4  __attribute__((ext_vector_type(4)));
typedef int    i32x8  __attribute__((ext_vector_type(8)));
typedef unsigned short u16x4 __attribute__((ext_vector_type(4)));
typedef unsigned int   u32x2 __attribute__((ext_vector_type(2)));

__device__ __forceinline__ unsigned short f2bf(float f) {
  unsigned int x = __float_as_uint(f);
  return (unsigned short)((x + 0x7fffu + ((x >> 16) & 1u)) >> 16);
}

__device__ __forceinline__ float bf2f(unsigned short u) {
  return __uint_as_float(((unsigned int)u) << 16);
}

__device__ __forceinline__ unsigned int pk_bf16(float a, float b) {
  return (unsigned int)f2bf(a) | ((unsigned int)f2bf(b) << 16);
}

// Software fp32 -> OCP e4m3fn, RNE, for v >= 0 (all values < 1.2).
__device__ __forceinline__ unsigned char f2fp8(float v) {
  if (v < 0.015625f) {
    return (unsigned char)__float2int_rn(v * 512.0f);
  }
  unsigned int u = __float_as_uint(v);
  u += 0x7ffffu + ((u >> 20) & 1u);
  int e = (int)(u >> 23) - 127 + 7;
  unsigned int m = (u >> 20) & 7u;
  return (unsigned char)((e << 3) | m);
}

__device__ __forceinline__ float basis_f(float t, int j) {
  switch (j) {
    case 0: return 1.0f;
    case 1: return t;
    case 2: return t * t;
    case 3: { float r = t - 0.33f; r = r > 0.0f ? r : 0.0f; return r * r; }
    default:{ float r = t - 0.66f; r = r > 0.0f ? r : 0.0f; return r * r; }
  }
}

// ---------------------------------------------------------------------------
// prep_all v3 (unchanged — proven): kbDT (fp32 [d][b]) holds the
// TELESCOPING difference kb[b,d]-kb[b,d+1] (kbDT[24][b] = kb[b][24]).
// ---------------------------------------------------------------------------
__global__ __launch_bounds__(256) void prep_all_kernel(
    const float* __restrict__ x, const float* __restrict__ W,
    const float* __restrict__ bias, unsigned char* __restrict__ Xf8,
    float* __restrict__ kbDT, unsigned char* __restrict__ kbT8,
    unsigned char* __restrict__ Wf8, float* __restrict__ out)
{
  __shared__ unsigned char tile8[PWI * T8P];   // 7 KB
  const int bid = blockIdx.x;
  const int tid = threadIdx.x;

  if (bid < 512) {
    const int lane = tid & 63;
    #pragma unroll
    for (int rr = 0; rr < 2; ++rr) {
      const int b = bid * 8 + (tid >> 6) * 2 + rr;
      const float* xr = x + (size_t)b * XCOLS;
      const float* fp = xr + 2 + lane * 8;
      float2 a0 = *(const float2*)(fp + 0);
      float2 a1 = *(const float2*)(fp + 2);
      float2 a2 = *(const float2*)(fp + 4);
      float2 a3 = *(const float2*)(fp + 6);
      float xf[8] = {a0.x, a0.y, a1.x, a1.y, a2.x, a2.y, a3.x, a3.y};
      u32x2 pk;
      pk[0] = (unsigned int)f2fp8(xf[0]) | ((unsigned int)f2fp8(xf[1]) << 8) |
              ((unsigned int)f2fp8(xf[2]) << 16) | ((unsigned int)f2fp8(xf[3]) << 24);
      pk[1] = (unsigned int)f2fp8(xf[4]) | ((unsigned int)f2fp8(xf[5]) << 8) |
              ((unsigned int)f2fp8(xf[6]) << 16) | ((unsigned int)f2fp8(xf[7]) << 24);
      *reinterpret_cast<u32x2*>(Xf8 + (size_t)b * IND_ + lane * 8) = pk;

      float t0 = xr[0], t1 = xr[1];
      if (lane < 2) out[(size_t)b * XCOLS + lane] = (lane == 0) ? t0 : t1;
      {
        // telescoping difference dk_d = kv_d - kv_{d+1} (kv_25 := 0)
        int d1 = lane / 5, d2 = lane - d1 * 5;
        float kvd = basis_f(t0, d1) * basis_f(t1, d2);
        float kvn = 0.0f;
        if (lane < 24) {
          int e1 = (lane + 1) / 5, e2 = (lane + 1) - e1 * 5;
          kvn = basis_f(t0, e1) * basis_f(t1, e2);
        }
        if (lane < ND) kbDT[(size_t)lane * NB + b] = kvd - kvn;
      }
      {
        int ta = 2 * lane, tb = 2 * lane + 1;
        unsigned char ba = 0, bb = 0;
        if (ta < ND) { int d1 = ta / 5, d2 = ta - d1 * 5;
                       ba = f2fp8(basis_f(t0, d1) * basis_f(t1, d2)); }
        if (tb < ND) { int d1 = tb / 5, d2 = tb - d1 * 5;
                       bb = f2fp8(basis_f(t0, d1) * basis_f(t1, d2)); }
        *(unsigned short*)(kbT8 + (size_t)b * 128 + 2 * lane) =
            (unsigned short)ba | ((unsigned short)bb << 8);
      }
    }
  } else {
    const int pw = bid - 512;
    const int i0 = (pw & 7) * PWI;
    const int o0 = (pw >> 3) * PWO;

    for (int t = tid; t < PWI * (PWC / 4); t += 256) {
      int il = t / (PWC / 4);
      int c4 = t - il * (PWC / 4);
      float4 v = *(const float4*)(W + ((size_t)(i0 + il) * OUTD_ + o0) * ND + c4 * 4);
      unsigned int pk = (unsigned int)f2fp8(v.x) | ((unsigned int)f2fp8(v.y) << 8) |
                        ((unsigned int)f2fp8(v.z) << 16) | ((unsigned int)f2fp8(v.w) << 24);
      *(unsigned int*)&tile8[il * T8P + c4 * 4] = pk;
    }
    __syncthreads();

    for (int g = tid; g < PWC * (PWI / 8); g += 256) {
      int c  = g >> 3;
      int ig = g & 7;
      int d  = c % 25;
      int o_l = c / 25;
      unsigned long long v = 0;
      #pragma unroll
      for (int jj = 0; jj < 8; ++jj)
        v |= (unsigned long long)tile8[(ig * 8 + jj) * T8P + c] << (8 * jj);
      size_t rowb = (size_t)(o0 + o_l) * KT2B + (size_t)d * IND_ + i0;
      *reinterpret_cast<unsigned long long*>(Wf8 + rowb + ig * 8) = v;
    }

    if ((pw & 7) == 0) {
      int o = o0 + (tid >> 6);
      int p = tid & 63;
      int ta = 2 * p, tb = 2 * p + 1;
      unsigned char ba = (ta < ND) ? f2fp8(bias[o * ND + ta]) : (unsigned char)0;
      unsigned char bb = (tb < ND) ? f2fp8(bias[o * ND + tb]) : (unsigned char)0;
      *(unsigned short*)(Wf8 + (size_t)o * KT2B + KTOT + 2 * p) =
          (unsigned short)ba | ((unsigned short)bb << 8);
    }
  }
}

// ---------------------------------------------------------------------------
// gemm_mx v8: ALL-REGISTER dataflow (R4/R5-proven numerically), register
// demand HALVED so the unified-file split cannot spill.
//
// R23 post-mortem: CSV VGPR_Count excludes MFMA accumulators (R0: 112 while
// holding 128 acc regs) -> the reported 128 in v6/v7 is the ARCH half of
// the gfx950 unified file.  With acc+fin (128) in AGPRs, v7's arch demand
// (bfr 64 + abuf 32 + dk 8 + addr/temps ~20 ≈ 183) exceeded the 128-arch
// split -> ~55 regs spilled -> 80 MB scratch writes + in-loop scratch
// latency at 2 waves/SIMD = the whole 88 us.  launch_bounds couldn't fix
// a demand problem.
//
// v8: wave tile 32o x 64b (half of v7): bfr 32 + abuf 32 + dk 4 + addrs
// ~15 ≈ 100-115 arch, acc[2][4]+fin[2][4] = 64 AGPR, total ≈ 160 -> fits
// the arch split with slack, and at ~160 total the HW runs 3 waves/SIMD
// naturally.  Block = 4 waves = 64o x 128b; grid = 8(o) x 4(iw) x 32(b)
// = 1024 blocks.  id&7 = o-tile -> each XCD streams one 827 KB Wf8 panel
// + 2 MB Xf8 (L2-resident).  Everything else identical to v7: no LDS, no
// barriers, A double-buffered one iter ahead, telescoping dk flush, bias
// tail for iw==3.
// ---------------------------------------------------------------------------
__global__ __launch_bounds__(256, 2) void gemm_mx_kernel(
    const unsigned char* __restrict__ Wf8, const unsigned char* __restrict__ Xf8,
    const float* __restrict__ kbDT, const unsigned char* __restrict__ kbT8,
    unsigned short* __restrict__ Pb)
{
  const int tid  = threadIdx.x;
  const int lane = tid & 63;
  const int w    = tid >> 6;            // [0,4)
  const int l15  = lane & 15;
  const int quad = lane >> 4;

  const int id = blockIdx.x;            // [0,1024)
  const int ox = id & 7;                // o-tile [0,8)  (XCD-pinned)
  const int iw = (id >> 3) & 3;         // i-window (split) [0,4)
  const int by = id >> 5;               // b-tile [0,32)

  const int o0 = ox * BM;
  const int b0 = by * BN;
  const bool tail = (iw == 3);

  const int wo = (w & 1) * 32;          // wave's o-offset in block
  const int wb = (w >> 1) * 64;         // wave's b-offset in block

  // helper: load a 32-B fragment (one row's K-window) into i32x8
  auto load8 = [](const unsigned char* p) -> i32x8 {
    i32x4 lo = *reinterpret_cast<const i32x4*>(p);
    i32x4 hi = *reinterpret_cast<const i32x4*>(p + 16);
    i32x8 v;
    v[0] = lo[0]; v[1] = lo[1]; v[2] = lo[2]; v[3] = lo[3];
    v[4] = hi[0]; v[5] = hi[1]; v[6] = hi[2]; v[7] = hi[3];
    return v;
  };

  // ---- B fragments once (held for the whole kernel): 32 regs ----
  i32x8 bfr[4];
  #pragma unroll
  for (int nf = 0; nf < 4; ++nf)
    bfr[nf] = load8(Xf8 + (size_t)(b0 + wb + nf * 16 + l15) * IND_ + iw * 128 + quad * 32);

  // ---- A row pointers (mf = 0,1); advance +1024 per unrolled-2 pass ----
  const unsigned char* aP0 =
      Wf8 + (size_t)(o0 + wo + l15) * KT2B + iw * 128 + quad * 32;
  const unsigned char* aP1 = aP0 + (size_t)16 * KT2B;

  // ---- dk pointer: kbDT[d][b0 + wb + nf*16 + l15]; advance +NB per iter ----
  const float* dkP = kbDT + b0 + wb + l15;

  f32x4 acc[2][4], fin[2][4];
  #pragma unroll
  for (int mf = 0; mf < 2; ++mf)
    #pragma unroll
    for (int nf = 0; nf < 4; ++nf) { acc[mf][nf] = (f32x4)0.0f; fin[mf][nf] = (f32x4)0.0f; }

  // 8 MFMAs (telescoping: acc never reset) + dk-scaled flush into fin
  auto mfma_flush = [&](const i32x8 (&a)[2], const float (&dk)[4]) {
    #pragma unroll
    for (int mf = 0; mf < 2; ++mf)
      #pragma unroll
      for (int nf = 0; nf < 4; ++nf)
        acc[mf][nf] = __builtin_amdgcn_mfma_scale_f32_16x16x128_f8f6f4(
            a[mf], bfr[nf], acc[mf][nf],
            0, 0, 0, 0x7f7f7f7f, 0, 0x7f7f7f7f);
    #pragma unroll
    for (int mf = 0; mf < 2; ++mf)
      #pragma unroll
      for (int nf = 0; nf < 4; ++nf)
        #pragma unroll
        for (int r = 0; r < 4; ++r)
          fin[mf][nf][r] += dk[nf] * acc[mf][nf][r];
  };

  // ---- prologue: A(0) into buffer a0 ----
  i32x8 a0[2], a1[2];
  a0[0] = load8(aP0);
  a0[1] = load8(aP1);

  // ---- main loop: 24 iters in 12 unrolled-2 passes, static double-buffer.
  // Pass invariant: aP* point at A(n) col-base; dkP at dk(n) row.
  for (int pass = 0; pass < 12; ++pass) {
    // iter n (even): compute on a0, prefetch A(n+1) -> a1
    a1[0] = load8(aP0 + 512);
    a1[1] = load8(aP1 + 512);
    float dka[4];
    #pragma unroll
    for (int nf = 0; nf < 4; ++nf) dka[nf] = dkP[nf * 16];
    mfma_flush(a0, dka);

    // iter n+1 (odd): compute on a1, prefetch A(n+2) -> a0
    a0[0] = load8(aP0 + 1024);
    a0[1] = load8(aP1 + 1024);
    float dkb[4];
    #pragma unroll
    for (int nf = 0; nf < 4; ++nf) dkb[nf] = dkP[NB + nf * 16];
    mfma_flush(a1, dkb);

    aP0 += 1024; aP1 += 1024;
    dkP += 2 * NB;
  }

  // ---- peeled iter 24 (a0 holds A(24)); tail prefetch for iw==3 ----
  // aP* now point at A(24) col-base = iw*128 + 12288 (+row,quad).  For
  // iw==3 the bias block lives at col KTOT=12800 -> offset +128.
  if (tail) {
    a1[0] = load8(aP0 + 128);
    a1[1] = load8(aP1 + 128);
  }
  {
    float dkl[4];
    #pragma unroll
    for (int nf = 0; nf < 4; ++nf) dkl[nf] = dkP[nf * 16];
    mfma_flush(a0, dkl);
  }

  // ---- bias K-tail (iw==3): B = kbT8 fragments, accumulate into fin ----
  if (tail) {
    i32x8 bft[4];
    #pragma unroll
    for (int nf = 0; nf < 4; ++nf)
      bft[nf] = load8(kbT8 + (size_t)(b0 + wb + nf * 16 + l15) * 128 + quad * 32);
    #pragma unroll
    for (int mf = 0; mf < 2; ++mf)
      #pragma unroll
      for (int nf = 0; nf < 4; ++nf)
        fin[mf][nf] = __builtin_amdgcn_mfma_scale_f32_16x16x128_f8f6f4(
            a1[mf], bft[nf], fin[mf][nf],
            0, 0, 0, 0x7f7f7f7f, 0, 0x7f7f7f7f);
  }

  // ---- store partial as bf16 ----
  unsigned short* Pz = Pb + (size_t)iw * NB * OUTD_;
  #pragma unroll
  for (int mf = 0; mf < 2; ++mf)
    #pragma unroll
    for (int nf = 0; nf < 4; ++nf) {
      int bg = b0 + wb + nf * 16 + l15;
      int og = o0 + wo + mf * 16 + quad * 4;
      u32x2 pk;
      pk[0] = pk_bf16(fin[mf][nf][0], fin[mf][nf][1]);
      pk[1] = pk_bf16(fin[mf][nf][2], fin[mf][nf][3]);
      *reinterpret_cast<u32x2*>(&Pz[(size_t)bg * OUTD_ + og]) = pk;
    }
}

// ---------------------------------------------------------------------------
// epilogue: out[b][2+o..2+o+3] = relu(P0+P1+P2+P3)  (bias in K-tail)
// ---------------------------------------------------------------------------
__global__ __launch_bounds__(256) void epilogue_kernel(
    const unsigned short* __restrict__ Pb, float* __restrict__ out)
{
  const int idx = (blockIdx.x * 256 + threadIdx.x) * 4;   // < 4096*512
  const int b = idx >> 9;
  const int o = idx & 511;
  const size_t ps = (size_t)NB * OUTD_;
  float s[4] = {0.0f, 0.0f, 0.0f, 0.0f};
  #pragma unroll
  for (int z = 0; z < NSPL; ++z) {
    u16x4 v = *reinterpret_cast<const u16x4*>(&Pb[z * ps + idx]);
    #pragma unroll
    for (int e = 0; e < 4; ++e) s[e] += bf2f(v[e]);
  }
  float* op = out + (size_t)b * XCOLS + 2 + o;   // 8B-aligned
  float2 lo, hi;
  lo.x = s[0] > 0.0f ? s[0] : 0.0f;
  lo.y = s[1] > 0.0f ? s[1] : 0.0f;
  hi.x = s[2] > 0.0f ? s[2] : 0.0f;
  hi.y = s[3] > 0.0f ? s[3] : 0.0f;
  *(float2*)op = lo;
  *(float2*)(op + 2) = hi;
}

// ---------------------------------------------------------------------------
extern "C" void kernel_launch(void* const* d_in, const int* in_sizes, int n_in,
                              void* d_out, int out_size, void* d_ws, size_t ws_size,
                              hipStream_t stream) {
  const float* x    = (const float*)d_in[0];   // 4096 x 514
  const float* W    = (const float*)d_in[1];   // 512 x 512 x 25
  const float* bias = (const float*)d_in[2];   // 512 x 25
  float* out = (float*)d_out;
  char* ws = (char*)d_ws;

  // ws layout (bytes):
  //   Xf8 2,097,152 | Wf8 512*12928 = 6,619,136 | kbDT 25*4096*4 = 409,600
  //   kbT8 524,288 | Pb 4*4096*512*2 = 16,777,216   (total ~26.4 MB)
  const size_t xf_off  = 0;
  const size_t wf_off  = 2097152;
  const size_t kb_off  = wf_off + (size_t)OUTD_ * KT2B;
  const size_t kbt_off = kb_off + 409600;
  const size_t p_off   = kbt_off + (size_t)NB * 128;
  unsigned char* Xf8  = (unsigned char*)(ws + xf_off);
  unsigned char* Wf8  = (unsigned char*)(ws + wf_off);
  float* kbDT         = (float*)(ws + kb_off);
  unsigned char* kbT8 = (unsigned char*)(ws + kbt_off);
  unsigned short* Pb  = (unsigned short*)(ws + p_off);

  prep_all_kernel<<<1536, 256, 0, stream>>>(x, W, bias, Xf8, kbDT, kbT8, Wf8, out);
  gemm_mx_kernel<<<1024, 256, 0, stream>>>(Wf8, Xf8, kbDT, kbT8, Pb);
  epilogue_kernel<<<(NB * OUTD_) / 1024, 256, 0, stream>>>(Pb, out);
}